// Round 2
// baseline (309.227 us; speedup 1.0000x reference)
//
#include <hip/hip_runtime.h>

#define POOL 7
#define NROIS 1000
#define NCELLS (NROIS * POOL * POOL)     // 49000 output cells
#define IMG_W 128
#define NCH 1024
#define NXCD 8
#define ROIS_PER_XCD (NROIS / NXCD)      // 125
#define CELLS_PER_XCD (ROIS_PER_XCD * 49) // 6125

typedef float f4 __attribute__((ext_vector_type(4)));

// One output cell (= one 1024-channel row, 4 KB) per 256-thread block.
// Each block: 4 fully-coalesced 4 KB corner-row reads + 1 contiguous 4 KB
// nontemporal store. ROI record + coordinate math are block-uniform (scalar
// path). XCD swizzle (bid&7 round-robin heuristic) gives each XCD a
// contiguous range of 125 ROIs, so the 49 cells of an ROI share their
// corner rows in that XCD's L2; cross-ROI overlap is served by the 256 MB
// L3 (image = 64 MB, fully L3-resident).
__global__ __launch_bounds__(256) void roi_pool_kernel(
    const float* __restrict__ img,
    const int* __restrict__ rois,
    float* __restrict__ out)
{
    const unsigned bid  = blockIdx.x;
    const unsigned xcd  = bid & 7u;            // presumed XCD of this block
    const unsigned slot = bid >> 3;            // 0..6124 within XCD
    const unsigned rloc = slot / 49u;          // local ROI index
    const unsigned c49  = slot - rloc * 49u;   // cell within ROI
    const unsigned roi  = xcd * ROIS_PER_XCD + rloc;
    const unsigned py   = c49 / 7u;
    const unsigned px   = c49 - py * 7u;

    // Block-uniform ROI record -> scalar load
    const int4 r = ((const int4*)rois)[roi];   // x, y, w, h
    const int x = r.x, y = r.y, w = r.z, h = r.w;

    // y-axis source coords (match reference op order exactly)
    const float hf = (float)h;
    float fy = ((float)py + 0.5f) * (hf / (float)POOL) - 0.5f;
    fy = fminf(fmaxf(fy, 0.0f), fmaxf(hf - 1.0f, 0.0f));
    const int   iy0 = (int)floorf(fy);
    const int   iy1 = min(iy0 + 1, h - 1);
    const float wy  = fy - (float)iy0;
    const int   y0  = y + iy0;
    const int   y1  = y + iy1;

    // x-axis source coords
    const float wf = (float)w;
    float fx = ((float)px + 0.5f) * (wf / (float)POOL) - 0.5f;
    fx = fminf(fmaxf(fx, 0.0f), fmaxf(wf - 1.0f, 0.0f));
    const int   ix0 = (int)floorf(fx);
    const int   ix1 = min(ix0 + 1, w - 1);
    const float wx  = fx - (float)ix0;
    const int   x0  = x + ix0;
    const int   x1  = x + ix1;

    // Each thread handles 4 consecutive channels; 256 threads cover 1024.
    const unsigned choff = threadIdx.x * 4u;
    const unsigned cell  = roi * 49u + c49;

    const f4* p00 = (const f4*)(img + ((size_t)y0 * IMG_W + x0) * NCH + choff);
    const f4* p01 = (const f4*)(img + ((size_t)y0 * IMG_W + x1) * NCH + choff);
    const f4* p10 = (const f4*)(img + ((size_t)y1 * IMG_W + x0) * NCH + choff);
    const f4* p11 = (const f4*)(img + ((size_t)y1 * IMG_W + x1) * NCH + choff);
    f4* po = (f4*)(out + (size_t)cell * NCH + choff);

    const f4 a = *p00;
    const f4 b = *p01;
    const f4 c = *p10;
    const f4 d = *p11;

    const float owx = 1.0f - wx;
    const float owy = 1.0f - wy;

    const f4 top = a * owx + b * wx;
    const f4 bot = c * owx + d * wx;
    const f4 res = top * owy + bot * wy;

    __builtin_nontemporal_store(res, po);
}

extern "C" void kernel_launch(void* const* d_in, const int* in_sizes, int n_in,
                              void* d_out, int out_size, void* d_ws, size_t ws_size,
                              hipStream_t stream)
{
    const float* img  = (const float*)d_in[0];
    const int*   rois = (const int*)d_in[1];
    float*       out  = (float*)d_out;

    const int nblocks = CELLS_PER_XCD * NXCD;  // 49000
    roi_pool_kernel<<<nblocks, 256, 0, stream>>>(img, rois, out);
}